// Round 1
// baseline (3122.345 us; speedup 1.0000x reference)
//
#include <hip/hip_runtime.h>

// ---------------------------------------------------------------------------
// Problem constants
// ---------------------------------------------------------------------------
static constexpr int NROWS = 65536;
static constexpr int DIN   = 768;

// ---------------------------------------------------------------------------
// Workspace layout (float offsets)
// ---------------------------------------------------------------------------
static constexpr size_t PSUM   = 0;                                    // 256*768
static constexpr size_t PSUM2  = PSUM  + (size_t)256 * 768;            // 256*768
static constexpr size_t SFOLD  = PSUM2 + (size_t)256 * 768;            // 768
static constexpr size_t TFOLD  = SFOLD + 768;                          // 768
static constexpr size_t WG0    = TFOLD + 768;                          // 3*512*768
static constexpr size_t BG0    = WG0   + (size_t)3 * 512 * 768;        // 1536
static constexpr size_t WG1    = BG0   + 1536;                         // 3*512*512
static constexpr size_t BG1    = WG1   + (size_t)3 * 512 * 512;        // 1536
static constexpr size_t H1OFF  = BG1   + 1536;                         // 65536*512
static constexpr size_t EOFF   = H1OFF + (size_t)NROWS * 512;          // 65536*2
static constexpr size_t PMATO  = EOFF  + (size_t)NROWS * 2;            // 1024*4
static constexpr size_t NUMACC = PMATO + 1024 * 4;                     // 1
// total ~36.05M floats = ~138 MB of d_ws

// ---------------------------------------------------------------------------
// Device helpers
// ---------------------------------------------------------------------------
__device__ __forceinline__ float sigm_(float x) { return 1.f / (1.f + __expf(-x)); }
__device__ __forceinline__ float tanh_(float x) {
  x = fminf(fmaxf(x, -15.f), 15.f);
  float e = __expf(2.f * x);
  return (e - 1.f) / (e + 1.f);
}
// stable logsumexp of two
__device__ __forceinline__ float lse2_(float a, float b) {
  float m = fmaxf(a, b);
  float d = fabsf(a - b);
  return m + log1pf(expf(-d));
}

// ---------------------------------------------------------------------------
// BatchNorm statistics: partial sums per 256-row chunk
// grid (3, 256), block 256. ws[PSUM/PSUM2][chunk][d]
// ---------------------------------------------------------------------------
__global__ __launch_bounds__(256) void bn_partial(const float* __restrict__ x,
                                                  float* __restrict__ ws) {
  int d = blockIdx.x * 256 + threadIdx.x;          // 0..767
  int chunk = blockIdx.y;                          // 0..255
  const float* p = x + (size_t)chunk * 256 * DIN + d;
  float s = 0.f, s2 = 0.f;
  #pragma unroll 8
  for (int r = 0; r < 256; ++r) {
    float v = p[(size_t)r * DIN];
    s += v;
    s2 = fmaf(v, v, s2);
  }
  ws[PSUM  + (size_t)chunk * DIN + d] = s;
  ws[PSUM2 + (size_t)chunk * DIN + d] = s2;
}

// grid 3, block 256: finalize mu/var -> folded scale s[d] and shift t[d]
__global__ __launch_bounds__(256) void bn_finalize(const float* __restrict__ gamma,
                                                   const float* __restrict__ beta,
                                                   float* __restrict__ ws) {
  int d = blockIdx.x * 256 + threadIdx.x;
  float s = 0.f, s2 = 0.f;
  for (int c = 0; c < 256; ++c) {
    s  += ws[PSUM  + (size_t)c * DIN + d];
    s2 += ws[PSUM2 + (size_t)c * DIN + d];
  }
  float mu  = s  * (1.f / NROWS);
  float var = s2 * (1.f / NROWS) - mu * mu;
  float sf  = rsqrtf(var + 1e-5f) * gamma[d];
  ws[SFOLD + d] = sf;                    // scale folded into weights
  ws[TFOLD + d] = beta[d] - mu * sf;     // shift folded into bias
}

// ---------------------------------------------------------------------------
// Weight prep, layer 0: gather used gates (i,g,o), fold BN scale into W,
// fold BN shift into bias. grid 1536 blocks x 256 threads; q = blockIdx.x.
// Wg0[q][d] layout: q = sect*512 + dir*256 + jj  (sect 0=i,1=g,2=o)
// ---------------------------------------------------------------------------
__global__ __launch_bounds__(256) void prep_w0(const float* __restrict__ w_ih,
                                               const float* __restrict__ b_ih,
                                               const float* __restrict__ b_hh,
                                               float* __restrict__ ws) {
  int q = blockIdx.x;
  int s = q >> 9, j = q & 511, dir = j >> 8, jj = j & 255;
  int goff = (s == 0) ? 0 : ((s == 1) ? 512 : 768);
  int row = dir * 1024 + goff + jj;
  const float* src = w_ih + (size_t)row * DIN;
  const float* sf = ws + SFOLD;
  const float* tf = ws + TFOLD;
  float* dst = ws + WG0 + (size_t)q * DIN;
  float acc = 0.f;
  for (int d = threadIdx.x; d < DIN; d += 256) {
    float w = src[d];
    dst[d] = w * sf[d];
    acc = fmaf(w, tf[d], acc);
  }
  // block reduce acc
  for (int off = 32; off; off >>= 1) acc += __shfl_down(acc, off);
  __shared__ float red[4];
  if ((threadIdx.x & 63) == 0) red[threadIdx.x >> 6] = acc;
  __syncthreads();
  if (threadIdx.x == 0)
    ws[BG0 + q] = red[0] + red[1] + red[2] + red[3] + b_ih[row] + b_hh[row];
}

// Weight prep, layer 1: pure gather of i,g,o rows (K=512). grid 1536 x 256.
__global__ __launch_bounds__(256) void prep_w1(const float* __restrict__ w_ih,
                                               const float* __restrict__ b_ih,
                                               const float* __restrict__ b_hh,
                                               float* __restrict__ ws) {
  int q = blockIdx.x;
  int s = q >> 9, j = q & 511, dir = j >> 8, jj = j & 255;
  int goff = (s == 0) ? 0 : ((s == 1) ? 512 : 768);
  int row = dir * 1024 + goff + jj;
  const float* src = w_ih + (size_t)row * 512;
  float* dst = ws + WG1 + (size_t)q * 512;
  for (int d = threadIdx.x; d < 512; d += 256) dst[d] = src[d];
  if (threadIdx.x == 0) ws[BG1 + q] = b_ih[row] + b_hh[row];
}

// init e[n][t] = fc_b[t]; zero the num accumulator. grid 512 x 256.
__global__ __launch_bounds__(256) void init_misc(const float* __restrict__ fc_b,
                                                 float* __restrict__ ws) {
  int i = blockIdx.x * 256 + threadIdx.x;
  if (i < NROWS * 2) ws[EOFF + i] = fc_b[i & 1];
  if (i == 0) ws[NUMACC] = 0.f;
}

// ---------------------------------------------------------------------------
// Fused gates GEMM: C[m][q] = A[m][:] . W[q][:] + bias[q], then LSTM act.
// BM=128 rows, BNH=64 h-cols (=> 192 gate cols), BK=16, 256 threads.
// Thread tile: 8 rows x 4 h-cols x 3 gates = 96 accumulators.
// EPI=0: write h (M x 512). EPI=1: fuse FC -> atomicAdd into e (M x 2).
// ---------------------------------------------------------------------------
template <int K, int EPI>
__global__ __launch_bounds__(256) void gates_gemm(const float* __restrict__ A,
                                                  const float* __restrict__ W,
                                                  const float* __restrict__ bg,
                                                  float* __restrict__ hout,
                                                  const float* __restrict__ fcw,
                                                  float* __restrict__ ew) {
  constexpr int BM = 128, BNH = 64, BK = 16;
  __shared__ float As[BK][BM + 4];   // [k][m], pad to dodge store conflicts
  __shared__ float Bs[BK][192 + 4];  // [k][sect*64+j]

  const int tid = threadIdx.x;
  const int tn = tid & 15, tm = tid >> 4;
  const int m0 = blockIdx.y * BM;
  const int c0 = blockIdx.x * BNH;

  float acc[3][8][4] = {};

  for (int k0 = 0; k0 < K; k0 += BK) {
    // ---- stage A tile: 128x16 = 512 float4, 2 per thread
    #pragma unroll
    for (int p = 0; p < 2; ++p) {
      int i = tid + p * 256;
      int row = i >> 2, c4 = (i & 3) << 2;
      const float4 v = *(const float4*)(A + (size_t)(m0 + row) * K + k0 + c4);
      As[c4 + 0][row] = v.x; As[c4 + 1][row] = v.y;
      As[c4 + 2][row] = v.z; As[c4 + 3][row] = v.w;
    }
    // ---- stage B tile: 192x16 = 768 float4, 3 per thread
    #pragma unroll
    for (int p = 0; p < 3; ++p) {
      int i = tid + p * 256;
      int brow = i >> 2, c4 = (i & 3) << 2;
      int s = brow >> 6, j = brow & 63;
      const float4 v = *(const float4*)(W + (size_t)(s * 512 + c0 + j) * K + k0 + c4);
      Bs[c4 + 0][brow] = v.x; Bs[c4 + 1][brow] = v.y;
      Bs[c4 + 2][brow] = v.z; Bs[c4 + 3][brow] = v.w;
    }
    __syncthreads();
    #pragma unroll
    for (int k = 0; k < BK; ++k) {
      const float4 a0 = *(const float4*)&As[k][tm * 8];
      const float4 a1 = *(const float4*)&As[k][tm * 8 + 4];
      const float a[8] = {a0.x, a0.y, a0.z, a0.w, a1.x, a1.y, a1.z, a1.w};
      #pragma unroll
      for (int s = 0; s < 3; ++s) {
        const float4 bv = *(const float4*)&Bs[k][s * 64 + tn * 4];
        const float b[4] = {bv.x, bv.y, bv.z, bv.w};
        #pragma unroll
        for (int r = 0; r < 8; ++r)
          #pragma unroll
          for (int c = 0; c < 4; ++c)
            acc[s][r][c] = fmaf(a[r], b[c], acc[s][r][c]);
      }
    }
    __syncthreads();
  }

  // ---- epilogue: LSTM cell activation (f-gate dead since c0=0)
  float h[8][4];
  #pragma unroll
  for (int c = 0; c < 4; ++c) {
    const int jc = c0 + tn * 4 + c;
    const float bi = bg[jc], bgg = bg[512 + jc], bo = bg[1024 + jc];
    #pragma unroll
    for (int r = 0; r < 8; ++r) {
      float gi = acc[0][r][c] + bi;
      float gg = acc[1][r][c] + bgg;
      float go = acc[2][r][c] + bo;
      float cc = sigm_(gi) * tanh_(gg);
      h[r][c] = sigm_(go) * tanh_(cc);
    }
  }

  if constexpr (EPI == 0) {
    #pragma unroll
    for (int r = 0; r < 8; ++r) {
      float4 hv = make_float4(h[r][0], h[r][1], h[r][2], h[r][3]);
      *(float4*)(hout + (size_t)(m0 + tm * 8 + r) * 512 + c0 + tn * 4) = hv;
    }
  } else {
    // fused FC: pe[r][t] = sum_c h[r][c] * fc_w[t][col]; reduce over 16 tn lanes
    float fw0[4], fw1[4];
    #pragma unroll
    for (int c = 0; c < 4; ++c) {
      fw0[c] = fcw[c0 + tn * 4 + c];
      fw1[c] = fcw[512 + c0 + tn * 4 + c];
    }
    #pragma unroll
    for (int r = 0; r < 8; ++r) {
      float pe0 = 0.f, pe1 = 0.f;
      #pragma unroll
      for (int c = 0; c < 4; ++c) {
        pe0 = fmaf(h[r][c], fw0[c], pe0);
        pe1 = fmaf(h[r][c], fw1[c], pe1);
      }
      #pragma unroll
      for (int off = 1; off < 16; off <<= 1) {
        pe0 += __shfl_xor(pe0, off);
        pe1 += __shfl_xor(pe1, off);
      }
      if (tn == 0) {
        float* e = ew + (size_t)(m0 + tm * 8 + r) * 2;
        atomicAdd(e + 0, pe0);
        atomicAdd(e + 1, pe1);
      }
    }
  }
}

// ---------------------------------------------------------------------------
// CRF: log-semiring 2x2 partial products over chunks of 64 steps
// grid 4 x 256 => 1024 threads; thread g handles t in [1+g*64, 1+(g+1)*64)
// Also accumulates the "num" path terms (emission + transition scores).
// ---------------------------------------------------------------------------
__global__ __launch_bounds__(256) void crf_partial(const float* __restrict__ ew,
                                                   const int* __restrict__ labels,
                                                   const float* __restrict__ trans,
                                                   float* __restrict__ ws) {
  int g = blockIdx.x * 256 + threadIdx.x;   // 0..1023
  int t0 = 1 + g * 64;
  int t1 = t0 + 64; if (t1 > NROWS) t1 = NROWS;
  const float t00 = trans[0], t01 = trans[1], t10 = trans[2], t11 = trans[3];
  float p00 = 0.f, p01 = -1e30f, p10 = -1e30f, p11 = 0.f;   // identity
  float num = 0.f;
  int prev = labels[t0 - 1];
  for (int t = t0; t < t1; ++t) {
    float e0 = ew[(size_t)t * 2], e1 = ew[(size_t)t * 2 + 1];
    float m00 = t00 + e0, m01 = t01 + e1, m10 = t10 + e0, m11 = t11 + e1;
    float n00 = lse2_(p00 + m00, p01 + m10);
    float n01 = lse2_(p00 + m01, p01 + m11);
    float n10 = lse2_(p10 + m00, p11 + m10);
    float n11 = lse2_(p10 + m01, p11 + m11);
    p00 = n00; p01 = n01; p10 = n10; p11 = n11;
    int cur = labels[t];
    num += (cur ? e1 : e0) + trans[prev * 2 + cur];
    prev = cur;
  }
  float* pm = ws + PMATO + (size_t)g * 4;
  pm[0] = p00; pm[1] = p01; pm[2] = p10; pm[3] = p11;
  for (int off = 32; off; off >>= 1) num += __shfl_down(num, off);
  if ((threadIdx.x & 63) == 0) atomicAdd(ws + NUMACC, num);
}

// order-preserving tree reduce of the 1024 partial matrices + final loss
__global__ __launch_bounds__(256) void crf_final(const float* __restrict__ ew,
                                                 const int* __restrict__ labels,
                                                 const float* __restrict__ cstart,
                                                 const float* __restrict__ cend,
                                                 float* __restrict__ ws,
                                                 float* __restrict__ out) {
  __shared__ float sm[256][4];
  int t = threadIdx.x;
  const float* pm = ws + PMATO + (size_t)t * 4 * 4;
  float p00 = pm[0], p01 = pm[1], p10 = pm[2], p11 = pm[3];
  #pragma unroll
  for (int u = 1; u < 4; ++u) {
    const float* q = pm + u * 4;
    float b00 = q[0], b01 = q[1], b10 = q[2], b11 = q[3];
    float n00 = lse2_(p00 + b00, p01 + b10);
    float n01 = lse2_(p00 + b01, p01 + b11);
    float n10 = lse2_(p10 + b00, p11 + b10);
    float n11 = lse2_(p10 + b01, p11 + b11);
    p00 = n00; p01 = n01; p10 = n10; p11 = n11;
  }
  sm[t][0] = p00; sm[t][1] = p01; sm[t][2] = p10; sm[t][3] = p11;
  __syncthreads();
  for (int s = 1; s < 256; s <<= 1) {
    int i = t * (s << 1);
    if (i + s < 256) {
      float a00 = sm[i][0], a01 = sm[i][1], a10 = sm[i][2], a11 = sm[i][3];
      float b00 = sm[i + s][0], b01 = sm[i + s][1], b10 = sm[i + s][2], b11 = sm[i + s][3];
      sm[i][0] = lse2_(a00 + b00, a01 + b10);
      sm[i][1] = lse2_(a00 + b01, a01 + b11);
      sm[i][2] = lse2_(a10 + b00, a11 + b10);
      sm[i][3] = lse2_(a10 + b01, a11 + b11);
    }
    __syncthreads();
  }
  if (t == 0) {
    float a0 = cstart[0] + ew[0];
    float a1 = cstart[1] + ew[1];
    float aN0 = lse2_(a0 + sm[0][0], a1 + sm[0][2]);
    float aN1 = lse2_(a0 + sm[0][1], a1 + sm[0][3]);
    float den = lse2_(aN0 + cend[0], aN1 + cend[1]);
    int tag0 = labels[0], tagN = labels[NROWS - 1];
    float num = ws[NUMACC] + cstart[tag0] + ew[tag0] + cend[tagN];
    out[0] = den - num;   // loss = -(num - den)
  }
}

// copy e -> logits (out + 1). grid 512 x 256.
__global__ __launch_bounds__(256) void copy_logits(const float* __restrict__ ew,
                                                   float* __restrict__ out) {
  int i = blockIdx.x * 256 + threadIdx.x;
  if (i < NROWS * 2) out[1 + i] = ew[i];
}

// ---------------------------------------------------------------------------
// Launch
// ---------------------------------------------------------------------------
extern "C" void kernel_launch(void* const* d_in, const int* in_sizes, int n_in,
                              void* d_out, int out_size, void* d_ws, size_t ws_size,
                              hipStream_t stream) {
  const float* x        = (const float*)d_in[0];
  const float* gamma    = (const float*)d_in[1];
  const float* beta     = (const float*)d_in[2];
  const float* w_ih_l0  = (const float*)d_in[3];
  // d_in[4] w_hh_l0: dead (h0 == 0)
  const float* b_ih_l0  = (const float*)d_in[5];
  const float* b_hh_l0  = (const float*)d_in[6];
  const float* w_ih_l1  = (const float*)d_in[7];
  // d_in[8] w_hh_l1: dead
  const float* b_ih_l1  = (const float*)d_in[9];
  const float* b_hh_l1  = (const float*)d_in[10];
  const float* fc_w     = (const float*)d_in[11];
  const float* fc_b     = (const float*)d_in[12];
  const float* crf_start= (const float*)d_in[13];
  const float* crf_end  = (const float*)d_in[14];
  const float* crf_trans= (const float*)d_in[15];
  const int*   labels   = (const int*)d_in[16];

  float* ws  = (float*)d_ws;
  float* out = (float*)d_out;

  bn_partial<<<dim3(3, 256), 256, 0, stream>>>(x, ws);
  bn_finalize<<<3, 256, 0, stream>>>(gamma, beta, ws);
  prep_w0<<<1536, 256, 0, stream>>>(w_ih_l0, b_ih_l0, b_hh_l0, ws);
  prep_w1<<<1536, 256, 0, stream>>>(w_ih_l1, b_ih_l1, b_hh_l1, ws);
  init_misc<<<512, 256, 0, stream>>>(fc_b, ws);

  gates_gemm<768, 0><<<dim3(8, 512), 256, 0, stream>>>(
      x, ws + WG0, ws + BG0, ws + H1OFF, nullptr, nullptr);
  gates_gemm<512, 1><<<dim3(8, 512), 256, 0, stream>>>(
      ws + H1OFF, ws + WG1, ws + BG1, nullptr, fc_w, ws + EOFF);

  crf_partial<<<4, 256, 0, stream>>>(ws + EOFF, labels, crf_trans, ws);
  crf_final<<<1, 256, 0, stream>>>(ws + EOFF, labels, crf_start, crf_end, ws, out);
  copy_logits<<<512, 256, 0, stream>>>(ws + EOFF, out);
}

// Round 2
// 1266.099 us; speedup vs baseline: 2.4661x; 2.4661x over previous
//
#include <hip/hip_runtime.h>

typedef _Float16 f16x8 __attribute__((ext_vector_type(8)));
typedef _Float16 f16x4 __attribute__((ext_vector_type(4)));
typedef float f32x4 __attribute__((ext_vector_type(4)));

static constexpr int NROWS = 65536;

// ---------------------------------------------------------------------------
// Workspace byte offsets (total 142,635,264 B < proven-available 144,214,020 B)
// ---------------------------------------------------------------------------
static constexpr size_t OB_BG0  = 0;                        // 1536*4
static constexpr size_t OB_BG1  = OB_BG0 + 6144;            // 1536*4
static constexpr size_t OB_W1H  = OB_BG1 + 6144;            // 1536*768*2
static constexpr size_t OB_W1L  = OB_W1H + 2359296;
static constexpr size_t OB_W2H  = OB_W1L + 2359296;         // 1536*512*2
static constexpr size_t OB_W2L  = OB_W2H + 1572864;
static constexpr size_t OB_E    = OB_W2L + 1572864;         // 65536*2*4
static constexpr size_t OB_PMAT = OB_E + 524288;            // 1024*4*4
static constexpr size_t OB_NUM  = OB_PMAT + 16384;          // 256 (padded)
static constexpr size_t OB_HH   = OB_NUM + 256;             // 65536*512*2
static constexpr size_t OB_HL   = OB_HH + 67108864;         // 65536*512*2
// Aliased into the H region — all consumers finish before gemm1 writes H:
static constexpr size_t OB_PSUM  = OB_HH;                   // 256*768*4
static constexpr size_t OB_PSUM2 = OB_PSUM + 786432;        // 256*768*4
static constexpr size_t OB_SF    = OB_PSUM2 + 786432;       // 768*4
static constexpr size_t OB_TF    = OB_SF + 3072;            // 768*4

// ---------------------------------------------------------------------------
// Helpers
// ---------------------------------------------------------------------------
__device__ __forceinline__ float sigm_(float x) { return 1.f / (1.f + __expf(-x)); }
__device__ __forceinline__ float tanh_(float x) {
  x = fminf(fmaxf(x, -15.f), 15.f);
  float e = __expf(2.f * x);
  return (e - 1.f) / (e + 1.f);
}
__device__ __forceinline__ float lse2_(float a, float b) {
  float m = fmaxf(a, b);
  float d = fabsf(a - b);
  return m + log1pf(expf(-d));
}
// async global->LDS, 16B per lane; lds dest must be wave-uniform base
__device__ __forceinline__ void gload16(const void* g, void* l) {
  __builtin_amdgcn_global_load_lds(
      (const __attribute__((address_space(1))) void*)g,
      (__attribute__((address_space(3))) void*)l, 16, 0, 0);
}

// ---------------------------------------------------------------------------
// BatchNorm statistics
// ---------------------------------------------------------------------------
__global__ __launch_bounds__(256) void bn_partial(const float* __restrict__ x,
                                                  float* __restrict__ psum,
                                                  float* __restrict__ psum2) {
  int d = blockIdx.x * 256 + threadIdx.x;          // 0..767
  int chunk = blockIdx.y;                          // 0..255
  const float* p = x + (size_t)chunk * 256 * 768 + d;
  float s = 0.f, s2 = 0.f;
  #pragma unroll 8
  for (int r = 0; r < 256; ++r) {
    float v = p[(size_t)r * 768];
    s += v;
    s2 = fmaf(v, v, s2);
  }
  psum[(size_t)chunk * 768 + d] = s;
  psum2[(size_t)chunk * 768 + d] = s2;
}

__global__ __launch_bounds__(256) void bn_finalize(const float* __restrict__ gamma,
                                                   const float* __restrict__ beta,
                                                   const float* __restrict__ psum,
                                                   const float* __restrict__ psum2,
                                                   float* __restrict__ sf_out,
                                                   float* __restrict__ tf_out) {
  int d = blockIdx.x * 256 + threadIdx.x;
  float s = 0.f, s2 = 0.f;
  for (int c = 0; c < 256; ++c) {
    s  += psum[(size_t)c * 768 + d];
    s2 += psum2[(size_t)c * 768 + d];
  }
  float mu  = s  * (1.f / NROWS);
  float var = s2 * (1.f / NROWS) - mu * mu;
  float sf  = rsqrtf(var + 1e-5f) * gamma[d];
  sf_out[d] = sf;
  tf_out[d] = beta[d] - mu * sf;
}

// ---------------------------------------------------------------------------
// Weight prep L0: gather i,g,o rows, fold BN scale, split fp16 h/l, fold bias.
// q = sect*512 + dir*256 + jj
// ---------------------------------------------------------------------------
__global__ __launch_bounds__(256) void prep_w0(const float* __restrict__ w,
                                               const float* __restrict__ b_ih,
                                               const float* __restrict__ b_hh,
                                               const float* __restrict__ sf,
                                               const float* __restrict__ tf,
                                               _Float16* __restrict__ wh,
                                               _Float16* __restrict__ wl,
                                               float* __restrict__ bg) {
  int q = blockIdx.x;
  int s = q >> 9, j = q & 511, dir = j >> 8, jj = j & 255;
  int goff = (s == 0) ? 0 : ((s == 1) ? 512 : 768);
  int row = dir * 1024 + goff + jj;
  const float* src = w + (size_t)row * 768;
  float acc = 0.f;
  for (int d = threadIdx.x; d < 768; d += 256) {
    float wv = src[d];
    float wf = wv * sf[d];
    _Float16 h = (_Float16)wf;
    wh[(size_t)q * 768 + d] = h;
    wl[(size_t)q * 768 + d] = (_Float16)(wf - (float)h);
    acc = fmaf(wv, tf[d], acc);
  }
  for (int off = 32; off; off >>= 1) acc += __shfl_down(acc, off);
  __shared__ float red[4];
  if ((threadIdx.x & 63) == 0) red[threadIdx.x >> 6] = acc;
  __syncthreads();
  if (threadIdx.x == 0)
    bg[q] = red[0] + red[1] + red[2] + red[3] + b_ih[row] + b_hh[row];
}

// Weight prep L1: gather + split (no BN fold)
__global__ __launch_bounds__(256) void prep_w1(const float* __restrict__ w,
                                               const float* __restrict__ b_ih,
                                               const float* __restrict__ b_hh,
                                               _Float16* __restrict__ wh,
                                               _Float16* __restrict__ wl,
                                               float* __restrict__ bg) {
  int q = blockIdx.x;
  int s = q >> 9, j = q & 511, dir = j >> 8, jj = j & 255;
  int goff = (s == 0) ? 0 : ((s == 1) ? 512 : 768);
  int row = dir * 1024 + goff + jj;
  const float* src = w + (size_t)row * 512;
  for (int d = threadIdx.x; d < 512; d += 256) {
    float wv = src[d];
    _Float16 h = (_Float16)wv;
    wh[(size_t)q * 512 + d] = h;
    wl[(size_t)q * 512 + d] = (_Float16)(wv - (float)h);
  }
  if (threadIdx.x == 0) bg[q] = b_ih[row] + b_hh[row];
}

// e[n][t] = fc_b[t]; zero num accumulator
__global__ __launch_bounds__(256) void init_misc(const float* __restrict__ fc_b,
                                                 float* __restrict__ e,
                                                 float* __restrict__ num) {
  int i = blockIdx.x * 256 + threadIdx.x;
  if (i < NROWS * 2) e[i] = fc_b[i & 1];
  if (i == 0) num[0] = 0.f;
}

// ---------------------------------------------------------------------------
// MFMA compute core: wave tile 64 rows x 32 hcols x 3 gates, fp16 3-term split
// ---------------------------------------------------------------------------
__device__ __forceinline__ void mfma_core(const _Float16 (*Ah)[32], const _Float16 (*Al)[32],
                                          const _Float16 (*Bh)[32], const _Float16 (*Bl)[32],
                                          int wm, int wc, int l15, int lhi,
                                          f32x4 acc[4][3][2]) {
  f16x8 ah[4], al[4];
  #pragma unroll
  for (int mf = 0; mf < 4; ++mf) {
    ah[mf] = *(const f16x8*)&Ah[wm * 64 + mf * 16 + l15][lhi * 8];
    al[mf] = *(const f16x8*)&Al[wm * 64 + mf * 16 + l15][lhi * 8];
  }
  #pragma unroll
  for (int s = 0; s < 3; ++s)
    #pragma unroll
    for (int jf = 0; jf < 2; ++jf) {
      int br = s * 64 + wc * 32 + jf * 16 + l15;
      f16x8 bh = *(const f16x8*)&Bh[br][lhi * 8];
      f16x8 bl = *(const f16x8*)&Bl[br][lhi * 8];
      #pragma unroll
      for (int mf = 0; mf < 4; ++mf) {
        acc[mf][s][jf] = __builtin_amdgcn_mfma_f32_16x16x32_f16(ah[mf], bh, acc[mf][s][jf], 0, 0, 0);
        acc[mf][s][jf] = __builtin_amdgcn_mfma_f32_16x16x32_f16(ah[mf], bl, acc[mf][s][jf], 0, 0, 0);
        acc[mf][s][jf] = __builtin_amdgcn_mfma_f32_16x16x32_f16(al[mf], bh, acc[mf][s][jf], 0, 0, 0);
      }
    }
}

// ---------------------------------------------------------------------------
// GEMM1: gates = x @ W1' ; A (f32) reg-staged with on-the-fly fp16 split.
// Block: 128 rows x 64 hcols (192 gate cols). Epilogue: LSTM act -> Hh/Hl fp16.
// Grid (8, 512).
// ---------------------------------------------------------------------------
__global__ __launch_bounds__(256, 2) void gemm1(const float* __restrict__ A,
                                                const _Float16* __restrict__ Wh,
                                                const _Float16* __restrict__ Wl,
                                                const float* __restrict__ bg,
                                                _Float16* __restrict__ Hh,
                                                _Float16* __restrict__ Hl) {
  constexpr int K = 768;
  __shared__ __align__(16) _Float16 Ah[128][32], Al[128][32];   // 8 KB each
  __shared__ __align__(16) _Float16 Bh[192][32], Bl[192][32];   // 12 KB each

  const int tid = threadIdx.x;
  const int lane = tid & 63, wvid = tid >> 6;
  const int l15 = lane & 15, lhi = lane >> 4;
  const int wm = wvid >> 1, wc = wvid & 1;

  // XCD-bijective swizzle (4096 blocks, 8 XCDs)
  int bid = blockIdx.y * 8 + blockIdx.x;
  int wid = (bid & 7) * 512 + (bid >> 3);
  const int m0 = (wid >> 3) * 128;
  const int c0 = (wid & 7) * 64;

  f32x4 acc[4][3][2] = {};

  for (int k0 = 0; k0 < K; k0 += 32) {
    // ---- stage A: 128x32 f32 -> fp16 h/l (1024 float4, 4 per thread)
    #pragma unroll
    for (int p = 0; p < 4; ++p) {
      int i = tid + p * 256;
      int row = i >> 3, cc4 = i & 7;
      const float4 v = *(const float4*)(A + (size_t)(m0 + row) * K + k0 + cc4 * 4);
      f16x4 hv, lv;
      hv[0] = (_Float16)v.x; lv[0] = (_Float16)(v.x - (float)hv[0]);
      hv[1] = (_Float16)v.y; lv[1] = (_Float16)(v.y - (float)hv[1]);
      hv[2] = (_Float16)v.z; lv[2] = (_Float16)(v.z - (float)hv[2]);
      hv[3] = (_Float16)v.w; lv[3] = (_Float16)(v.w - (float)hv[3]);
      *(f16x4*)&Ah[row][cc4 * 4] = hv;
      *(f16x4*)&Al[row][cc4 * 4] = lv;
    }
    // ---- stage B: 192x32 fp16 h+l via global_load_lds (wave-uniform dest)
    #pragma unroll
    for (int it = 0; it < 3; ++it) {
      int g = wvid + it * 4;                 // 0..11
      int idx = g * 64 + lane;
      int brow = idx >> 2, kp = idx & 3;
      int s = brow >> 6, j = brow & 63;
      size_t off = (size_t)(s * 512 + c0 + j) * K + (k0 + kp * 8);
      gload16(Wh + off, (char*)Bh + g * 1024);
      gload16(Wl + off, (char*)Bl + g * 1024);
    }
    __syncthreads();
    mfma_core(Ah, Al, Bh, Bl, wm, wc, l15, lhi, acc);
    __syncthreads();
  }

  // ---- epilogue: LSTM cell (f-gate dead, c0=h0=0) -> h, split to fp16 h/l
  const int rb = m0 + wm * 64 + lhi * 4;
  #pragma unroll
  for (int mf = 0; mf < 4; ++mf)
    #pragma unroll
    for (int jf = 0; jf < 2; ++jf) {
      const int hcol = c0 + wc * 32 + jf * 16 + l15;
      const float bi = bg[hcol], bgv = bg[512 + hcol], bo = bg[1024 + hcol];
      #pragma unroll
      for (int r = 0; r < 4; ++r) {
        float gi = acc[mf][0][jf][r] + bi;
        float gg = acc[mf][1][jf][r] + bgv;
        float go = acc[mf][2][jf][r] + bo;
        float cv = sigm_(gi) * tanh_(gg);
        float h  = sigm_(go) * tanh_(cv);
        size_t o = (size_t)(rb + mf * 16 + r) * 512 + hcol;
        _Float16 hh = (_Float16)h;
        Hh[o] = hh;
        Hl[o] = (_Float16)(h - (float)hh);
      }
    }
}

// ---------------------------------------------------------------------------
// GEMM2: gates = h1 @ W2' ; A pre-split fp16 (Hh/Hl) via global_load_lds.
// Epilogue: LSTM act -> fused FC -> atomicAdd into e. Grid (8, 512).
// ---------------------------------------------------------------------------
__global__ __launch_bounds__(256, 2) void gemm2(const _Float16* __restrict__ Ahg,
                                                const _Float16* __restrict__ Alg,
                                                const _Float16* __restrict__ Wh,
                                                const _Float16* __restrict__ Wl,
                                                const float* __restrict__ bg,
                                                const float* __restrict__ fcw,
                                                float* __restrict__ ew) {
  constexpr int K = 512;
  __shared__ __align__(16) _Float16 Ah[128][32], Al[128][32];
  __shared__ __align__(16) _Float16 Bh[192][32], Bl[192][32];

  const int tid = threadIdx.x;
  const int lane = tid & 63, wvid = tid >> 6;
  const int l15 = lane & 15, lhi = lane >> 4;
  const int wm = wvid >> 1, wc = wvid & 1;

  int bid = blockIdx.y * 8 + blockIdx.x;
  int wid = (bid & 7) * 512 + (bid >> 3);
  const int m0 = (wid >> 3) * 128;
  const int c0 = (wid & 7) * 64;

  f32x4 acc[4][3][2] = {};

  for (int k0 = 0; k0 < K; k0 += 32) {
    // ---- stage A: 128x32 fp16 h+l via global_load_lds
    #pragma unroll
    for (int it = 0; it < 2; ++it) {
      int g = wvid + it * 4;                 // 0..7
      int idx = g * 64 + lane;
      int row = idx >> 2, kp = idx & 3;
      size_t off = (size_t)(m0 + row) * K + (k0 + kp * 8);
      gload16(Ahg + off, (char*)Ah + g * 1024);
      gload16(Alg + off, (char*)Al + g * 1024);
    }
    // ---- stage B
    #pragma unroll
    for (int it = 0; it < 3; ++it) {
      int g = wvid + it * 4;                 // 0..11
      int idx = g * 64 + lane;
      int brow = idx >> 2, kp = idx & 3;
      int s = brow >> 6, j = brow & 63;
      size_t off = (size_t)(s * 512 + c0 + j) * K + (k0 + kp * 8);
      gload16(Wh + off, (char*)Bh + g * 1024);
      gload16(Wl + off, (char*)Bl + g * 1024);
    }
    __syncthreads();
    mfma_core(Ah, Al, Bh, Bl, wm, wc, l15, lhi, acc);
    __syncthreads();
  }

  // ---- epilogue: LSTM act, fused FC (2 outputs), reduce 16 lanes, atomicAdd
  const int rb = m0 + wm * 64 + lhi * 4;
  #pragma unroll
  for (int mf = 0; mf < 4; ++mf) {
    float pe0[4] = {0.f, 0.f, 0.f, 0.f}, pe1[4] = {0.f, 0.f, 0.f, 0.f};
    #pragma unroll
    for (int jf = 0; jf < 2; ++jf) {
      const int hcol = c0 + wc * 32 + jf * 16 + l15;
      const float bi = bg[hcol], bgv = bg[512 + hcol], bo = bg[1024 + hcol];
      const float f0 = fcw[hcol], f1 = fcw[512 + hcol];
      #pragma unroll
      for (int r = 0; r < 4; ++r) {
        float gi = acc[mf][0][jf][r] + bi;
        float gg = acc[mf][1][jf][r] + bgv;
        float go = acc[mf][2][jf][r] + bo;
        float cv = sigm_(gi) * tanh_(gg);
        float h  = sigm_(go) * tanh_(cv);
        pe0[r] = fmaf(h, f0, pe0[r]);
        pe1[r] = fmaf(h, f1, pe1[r]);
      }
    }
    #pragma unroll
    for (int r = 0; r < 4; ++r) {
      float a0 = pe0[r], a1 = pe1[r];
      #pragma unroll
      for (int off = 1; off < 16; off <<= 1) {
        a0 += __shfl_xor(a0, off);
        a1 += __shfl_xor(a1, off);
      }
      if (l15 == 0) {
        int rowg = rb + mf * 16 + r;
        atomicAdd(&ew[(size_t)rowg * 2 + 0], a0);
        atomicAdd(&ew[(size_t)rowg * 2 + 1], a1);
      }
    }
  }
}

// ---------------------------------------------------------------------------
// CRF: log-semiring 2x2 partial products (64 steps per thread) + num terms
// ---------------------------------------------------------------------------
__global__ __launch_bounds__(256) void crf_partial(const float* __restrict__ ew,
                                                   const int* __restrict__ labels,
                                                   const float* __restrict__ trans,
                                                   float* __restrict__ pmat,
                                                   float* __restrict__ numacc) {
  int g = blockIdx.x * 256 + threadIdx.x;   // 0..1023
  int t0 = 1 + g * 64;
  int t1 = t0 + 64; if (t1 > NROWS) t1 = NROWS;
  const float t00 = trans[0], t01 = trans[1], t10 = trans[2], t11 = trans[3];
  float p00 = 0.f, p01 = -1e30f, p10 = -1e30f, p11 = 0.f;   // identity
  float num = 0.f;
  int prev = labels[t0 - 1];
  for (int t = t0; t < t1; ++t) {
    float e0 = ew[(size_t)t * 2], e1 = ew[(size_t)t * 2 + 1];
    float m00 = t00 + e0, m01 = t01 + e1, m10 = t10 + e0, m11 = t11 + e1;
    float n00 = lse2_(p00 + m00, p01 + m10);
    float n01 = lse2_(p00 + m01, p01 + m11);
    float n10 = lse2_(p10 + m00, p11 + m10);
    float n11 = lse2_(p10 + m01, p11 + m11);
    p00 = n00; p01 = n01; p10 = n10; p11 = n11;
    int cur = labels[t];
    num += (cur ? e1 : e0) + trans[prev * 2 + cur];
    prev = cur;
  }
  float* pm = pmat + (size_t)g * 4;
  pm[0] = p00; pm[1] = p01; pm[2] = p10; pm[3] = p11;
  for (int off = 32; off; off >>= 1) num += __shfl_down(num, off);
  if ((threadIdx.x & 63) == 0) atomicAdd(numacc, num);
}

__global__ __launch_bounds__(256) void crf_final(const float* __restrict__ ew,
                                                 const int* __restrict__ labels,
                                                 const float* __restrict__ cstart,
                                                 const float* __restrict__ cend,
                                                 const float* __restrict__ pmat,
                                                 const float* __restrict__ numacc,
                                                 float* __restrict__ out) {
  __shared__ float sm[256][4];
  int t = threadIdx.x;
  const float* pm = pmat + (size_t)t * 16;
  float p00 = pm[0], p01 = pm[1], p10 = pm[2], p11 = pm[3];
  #pragma unroll
  for (int u = 1; u < 4; ++u) {
    const float* q = pm + u * 4;
    float b00 = q[0], b01 = q[1], b10 = q[2], b11 = q[3];
    float n00 = lse2_(p00 + b00, p01 + b10);
    float n01 = lse2_(p00 + b01, p01 + b11);
    float n10 = lse2_(p10 + b00, p11 + b10);
    float n11 = lse2_(p10 + b01, p11 + b11);
    p00 = n00; p01 = n01; p10 = n10; p11 = n11;
  }
  sm[t][0] = p00; sm[t][1] = p01; sm[t][2] = p10; sm[t][3] = p11;
  __syncthreads();
  for (int s = 1; s < 256; s <<= 1) {
    int i = t * (s << 1);
    if (i + s < 256) {
      float a00 = sm[i][0], a01 = sm[i][1], a10 = sm[i][2], a11 = sm[i][3];
      float b00 = sm[i + s][0], b01 = sm[i + s][1], b10 = sm[i + s][2], b11 = sm[i + s][3];
      sm[i][0] = lse2_(a00 + b00, a01 + b10);
      sm[i][1] = lse2_(a00 + b01, a01 + b11);
      sm[i][2] = lse2_(a10 + b00, a11 + b10);
      sm[i][3] = lse2_(a10 + b01, a11 + b11);
    }
    __syncthreads();
  }
  if (t == 0) {
    float a0 = cstart[0] + ew[0];
    float a1 = cstart[1] + ew[1];
    float aN0 = lse2_(a0 + sm[0][0], a1 + sm[0][2]);
    float aN1 = lse2_(a0 + sm[0][1], a1 + sm[0][3]);
    float den = lse2_(aN0 + cend[0], aN1 + cend[1]);
    int tag0 = labels[0], tagN = labels[NROWS - 1];
    float num = numacc[0] + cstart[tag0] + ew[tag0] + cend[tagN];
    out[0] = den - num;   // loss = -(num - den)
  }
}

__global__ __launch_bounds__(256) void copy_logits(const float* __restrict__ ew,
                                                   float* __restrict__ out) {
  int i = blockIdx.x * 256 + threadIdx.x;
  if (i < NROWS * 2) out[1 + i] = ew[i];
}

// ---------------------------------------------------------------------------
// Launch
// ---------------------------------------------------------------------------
extern "C" void kernel_launch(void* const* d_in, const int* in_sizes, int n_in,
                              void* d_out, int out_size, void* d_ws, size_t ws_size,
                              hipStream_t stream) {
  const float* x        = (const float*)d_in[0];
  const float* gamma    = (const float*)d_in[1];
  const float* beta     = (const float*)d_in[2];
  const float* w_ih_l0  = (const float*)d_in[3];
  // d_in[4] w_hh_l0: dead (h0 == 0)
  const float* b_ih_l0  = (const float*)d_in[5];
  const float* b_hh_l0  = (const float*)d_in[6];
  const float* w_ih_l1  = (const float*)d_in[7];
  // d_in[8] w_hh_l1: dead
  const float* b_ih_l1  = (const float*)d_in[9];
  const float* b_hh_l1  = (const float*)d_in[10];
  const float* fc_w     = (const float*)d_in[11];
  const float* fc_b     = (const float*)d_in[12];
  const float* crf_start= (const float*)d_in[13];
  const float* crf_end  = (const float*)d_in[14];
  const float* crf_trans= (const float*)d_in[15];
  const int*   labels   = (const int*)d_in[16];

  char* ws   = (char*)d_ws;
  float* out = (float*)d_out;

  float*     bg0  = (float*)(ws + OB_BG0);
  float*     bg1  = (float*)(ws + OB_BG1);
  _Float16*  w1h  = (_Float16*)(ws + OB_W1H);
  _Float16*  w1l  = (_Float16*)(ws + OB_W1L);
  _Float16*  w2h  = (_Float16*)(ws + OB_W2H);
  _Float16*  w2l  = (_Float16*)(ws + OB_W2L);
  float*     e    = (float*)(ws + OB_E);
  float*     pmat = (float*)(ws + OB_PMAT);
  float*     num  = (float*)(ws + OB_NUM);
  _Float16*  hh   = (_Float16*)(ws + OB_HH);
  _Float16*  hl   = (_Float16*)(ws + OB_HL);
  float*     psum = (float*)(ws + OB_PSUM);
  float*     psum2= (float*)(ws + OB_PSUM2);
  float*     sf   = (float*)(ws + OB_SF);
  float*     tf   = (float*)(ws + OB_TF);

  bn_partial<<<dim3(3, 256), 256, 0, stream>>>(x, psum, psum2);
  bn_finalize<<<3, 256, 0, stream>>>(gamma, beta, psum, psum2, sf, tf);
  prep_w0<<<1536, 256, 0, stream>>>(w_ih_l0, b_ih_l0, b_hh_l0, sf, tf, w1h, w1l, bg0);
  prep_w1<<<1536, 256, 0, stream>>>(w_ih_l1, b_ih_l1, b_hh_l1, w2h, w2l, bg1);
  init_misc<<<512, 256, 0, stream>>>(fc_b, e, num);

  gemm1<<<dim3(8, 512), 256, 0, stream>>>(x, w1h, w1l, bg0, hh, hl);
  gemm2<<<dim3(8, 512), 256, 0, stream>>>(hh, hl, w2h, w2l, bg1, fc_w, e);

  crf_partial<<<4, 256, 0, stream>>>(e, labels, crf_trans, pmat, num);
  crf_final<<<1, 256, 0, stream>>>(e, labels, crf_start, crf_end, pmat, num, out);
  copy_logits<<<512, 256, 0, stream>>>(e, out);
}